// Round 1
// baseline (328.521 us; speedup 1.0000x reference)
//
#include <hip/hip_runtime.h>
#include <cstdint>

#define M_PTS 8192
#define N_QRY 8192
#define BATCH 4

// ---------------- K0a: pack (x, y, z, x^2+y^2+z^2) ----------------
__global__ void pack_pts(const float* __restrict__ src, float4* __restrict__ dst, int total) {
#pragma clang fp contract(off)
  int i = blockIdx.x * 256 + threadIdx.x;
  if (i >= total) return;
  int b = i >> 13, m = i & (M_PTS - 1);
  const float* s = src + (size_t)b * 3 * M_PTS;
  float x = s[m], y = s[M_PTS + m], z = s[2 * M_PTS + m];
  float ss = (x * x + y * y) + z * z;   // matches jnp.sum(pts**2, axis=1) order
  dst[i] = make_float4(x, y, z, ss);
}

// ---------------- K0b: transpose local_feat (B,64,M) -> (B,M,64) ----------------
__global__ void transpose_lf(const float* __restrict__ lf, float* __restrict__ lfT) {
  __shared__ float tile[64][65];
  int bb = blockIdx.x >> 7;
  int m0 = (blockIdx.x & 127) << 6;
  int tm = threadIdx.x & 63;
  int tc = threadIdx.x >> 6;
  const float* src = lf + (size_t)bb * 64 * M_PTS;
#pragma unroll
  for (int i = 0; i < 16; i++) {
    int ch = i * 4 + tc;
    tile[ch][tm] = src[(size_t)ch * M_PTS + m0 + tm];
  }
  __syncthreads();
  float* dst = lfT + ((size_t)bb * M_PTS + m0) * 64;
#pragma unroll
  for (int i = 0; i < 16; i++) {
    int mm = i * 4 + tc;
    dst[(size_t)mm * 64 + tm] = tile[tm][mm];
  }
}

// ---------------- K0c: fold BN into conv weights ----------------
__global__ void fold_kernel(const float* w0, const float* b0, const float* g0, const float* be0,
                            const float* m0, const float* v0,
                            const float* w1, const float* b1, const float* g1, const float* be1,
                            const float* m1, const float* v1,
                            float* w0f, float* b0f, float* w1T, float* b1f) {
  int t = threadIdx.x;
  if (t >= 64) return;
  float inv0 = g0[t] / sqrtf(v0[t] + 1e-5f);
  w0f[t * 3 + 0] = w0[t * 3 + 0] * inv0;
  w0f[t * 3 + 1] = w0[t * 3 + 1] * inv0;
  w0f[t * 3 + 2] = w0[t * 3 + 2] * inv0;
  b0f[t] = (b0[t] - m0[t]) * inv0 + be0[t];
  float inv1 = g1[t] / sqrtf(v1[t] + 1e-5f);
  for (int c = 0; c < 64; c++) w1T[c * 64 + t] = w1[t * 64 + c] * inv1;  // [cin][cout], bn-folded
  b1f[t] = (b1[t] - m1[t]) * inv1 + be1[t];
}

// ---------------- K1: exact KNN top-16 (one wave per query) ----------------
// Per half (4096 pts): lane caches its 64 distances in VGPRs, tracks lane-min.
// tau = 16th smallest of the 64 lane minima (>=16 candidates <= tau guaranteed).
// Pass B ballot-compacts survivors; final exact sorted top-16 via 16 rounds of
// wave-wide u64 (dist_bits, idx) min-extraction (lower-index tie-break = top_k stability).
__global__ void __launch_bounds__(256, 3) knn_kernel(const float4* __restrict__ pp,
                                                     const float4* __restrict__ qp,
                                                     int* __restrict__ knn) {
#pragma clang fp contract(off)
  __shared__ float4 spts[2048];                 // 32 KB staged point chunk
  __shared__ unsigned long long cand[4][128];   // 4 KB candidate buffers (per wave)
  const int tid = threadIdx.x;
  const int lane = tid & 63;
  const int wave = tid >> 6;
  const int gq = blockIdx.x * 4 + wave;
  const int b = gq >> 13;
  const float4 q4 = qp[gq];
  const float qx = q4.x, qy = q4.y, qz = q4.z, q2 = q4.w;
  const float4* pb = pp + ((size_t)b << 13);
  int cnt = 0;
  float dch[64];

#pragma unroll
  for (int h = 0; h < 2; h++) {
    float mn = 3.402823e38f;
#pragma unroll
    for (int c = 0; c < 2; c++) {
      const int pbase = h * 4096 + c * 2048;
      __syncthreads();
#pragma unroll
      for (int i = 0; i < 8; i++) spts[i * 256 + tid] = pb[pbase + i * 256 + tid];
      __syncthreads();
#pragma unroll
      for (int j = 0; j < 32; j++) {
        float4 p = spts[j * 64 + lane];
        float dot = (qx * p.x + qy * p.y) + qz * p.z;   // reference op order, no fma
        float d2 = (q2 + p.w) - 2.0f * dot;
        dch[c * 32 + j] = d2;
        mn = fminf(mn, d2);
      }
    }
    // tau = 16th smallest of 64 lane minima via bitonic sort across lanes
    float v = mn;
#pragma unroll
    for (int k = 2; k <= 64; k <<= 1) {
#pragma unroll
      for (int j = k >> 1; j >= 1; j >>= 1) {
        float pv = __shfl_xor(v, j);
        bool keepmin = (((lane & k) == 0) == ((lane & j) == 0));
        float lo = fminf(v, pv), hi = fmaxf(v, pv);
        v = keepmin ? lo : hi;
      }
    }
    float tau = __shfl(v, 15);
    // pass B: emit all d2 <= tau from the register cache
#pragma unroll
    for (int r = 0; r < 64; r++) {
      float d2 = dch[r];
      bool pred = (d2 <= tau);
      unsigned long long mask = __ballot(pred);
      if (mask) {
        int prefix = __builtin_amdgcn_mbcnt_hi((unsigned)(mask >> 32),
                     __builtin_amdgcn_mbcnt_lo((unsigned)mask, 0));
        if (pred) {
          int pos = cnt + prefix;
          if (pos < 128) {
            unsigned fb = __float_as_uint(d2);
            fb ^= (unsigned)((int)fb >> 31) | 0x80000000u;   // order-preserving float->uint
            int pidx = h * 4096 + (r >> 5) * 2048 + (r & 31) * 64 + lane;
            cand[wave][pos] = ((unsigned long long)fb << 32) | (unsigned)pidx;
          }
        }
        cnt += __popcll(mask);
      }
    }
  }
  __syncthreads();
  int E = cnt > 128 ? 128 : cnt;   // expected E ~ 36; >=32 guaranteed
  unsigned long long c0 = (lane < E) ? cand[wave][lane] : ~0ull;
  unsigned long long c1 = (lane + 64 < E) ? cand[wave][lane + 64] : ~0ull;
  unsigned myidx = 0;
#pragma unroll
  for (int t = 0; t < 16; t++) {
    unsigned long long m = c0 < c1 ? c0 : c1;
#pragma unroll
    for (int j = 1; j < 64; j <<= 1) {
      unsigned long long o = __shfl_xor(m, j);
      if (o < m) m = o;
    }
    if (lane == t) myidx = (unsigned)m;
    if (c0 == m) c0 = ~0ull;
    else if (c1 == m) c1 = ~0ull;
  }
  if (lane < 16) knn[(size_t)gq * 16 + lane] = (int)myidx;
}

// ---------------- K2: fused feature pipeline (one wave per query, lane = channel) ----------------
__global__ void __launch_bounds__(256, 4) feat_kernel(const float4* __restrict__ pp,
                                                      const float4* __restrict__ qp,
                                                      const int* __restrict__ knn,
                                                      const float* __restrict__ lfT,
                                                      const float* __restrict__ w1T,
                                                      const float* __restrict__ w0f,
                                                      const float* __restrict__ b0f,
                                                      const float* __restrict__ b1f,
                                                      const float* __restrict__ w2,
                                                      const float* __restrict__ b2,
                                                      float* __restrict__ out) {
  __shared__ float w1lds[4096];
  __shared__ float4 relbuf[4][16];
  __shared__ float4 f0v[4 * 64];
  __shared__ float outbuf[64 * 4];
  const int tid = threadIdx.x;
  const int lane = tid & 63;
  const int wave = tid >> 6;
  const int gq = blockIdx.x * 4 + wave;
  const int b = gq >> 13;

#pragma unroll
  for (int i = 0; i < 16; i++) w1lds[i * 256 + tid] = w1T[i * 256 + tid];

  const float4 q4 = qp[gq];
  int nk = knn[(size_t)gq * 16 + (lane & 15)];
  float4 pk = pp[((size_t)b << 13) + nk];
  if (lane < 16) relbuf[wave][lane] = make_float4(pk.x - q4.x, pk.y - q4.y, pk.z - q4.z, 0.0f);
  __syncthreads();

  // feat0 (conv0 + bn + relu) for channel c = lane, all 16 neighbors; max -> g; keep k<4
  const float w00 = w0f[lane * 3 + 0], w01 = w0f[lane * 3 + 1], w02 = w0f[lane * 3 + 2];
  const float bb0 = b0f[lane];
  float g = 0.0f;
  float f0 = 0, f1 = 0, f2 = 0, f3 = 0;
#pragma unroll
  for (int k = 0; k < 16; k++) {
    float4 r = relbuf[wave][k];
    float y = fmaxf(0.0f, w00 * r.x + w01 * r.y + w02 * r.z + bb0);
    g = fmaxf(g, y);
    if (k == 0) f0 = y; else if (k == 1) f1 = y; else if (k == 2) f2 = y; else if (k == 3) f3 = y;
  }
  f0v[wave * 64 + lane] = make_float4(f0, f1, f2, f3);
  __syncthreads();

  // conv1 (bn-folded) for out channel o = lane, k<4
  float a0 = 0, a1 = 0, a2 = 0, a3 = 0;
#pragma unroll 16
  for (int c2 = 0; c2 < 64; c2++) {
    float w = w1lds[c2 * 64 + lane];     // coalesced across lanes
    float4 f4 = f0v[wave * 64 + c2];     // broadcast
    a0 += w * f4.x; a1 += w * f4.y; a2 += w * f4.z; a3 += w * f4.w;
  }
  const float bb1 = b1f[lane];
  float r0 = fmaxf(0.0f, a0 + bb1);
  float r1 = fmaxf(0.0f, a1 + bb1);
  float r2 = fmaxf(0.0f, a2 + bb1);
  float r3 = fmaxf(0.0f, a3 + bb1);

  // patch features (contiguous 64-ch gather from transposed local_feat)
  const size_t lfb = (((size_t)b << 13)) * 64;
  int i0 = knn[(size_t)gq * 16 + 0];
  int i1 = knn[(size_t)gq * 16 + 1];
  int i2 = knn[(size_t)gq * 16 + 2];
  int i3 = knn[(size_t)gq * 16 + 3];
  float p0 = lfT[lfb + (size_t)i0 * 64 + lane];
  float p1 = lfT[lfb + (size_t)i1 * 64 + lane];
  float p2 = lfT[lfb + (size_t)i2 * 64 + lane];
  float p3 = lfT[lfb + (size_t)i3 * 64 + lane];

  // sigmoid gate: w2[0:64] . rf  +  w2[64:128] . g  + b2
  const float w2a = w2[lane], w2b = w2[64 + lane];
  float s0 = w2a * r0, s1 = w2a * r1, s2 = w2a * r2, s3 = w2a * r3, tg = w2b * g;
#pragma unroll
  for (int j = 1; j < 64; j <<= 1) {
    s0 += __shfl_xor(s0, j);
    s1 += __shfl_xor(s1, j);
    s2 += __shfl_xor(s2, j);
    s3 += __shfl_xor(s3, j);
    tg += __shfl_xor(tg, j);
  }
  const float bias2 = b2[0];
  float wk0 = 1.0f / (1.0f + __expf(-(s0 + tg + bias2)));
  float wk1 = 1.0f / (1.0f + __expf(-(s1 + tg + bias2)));
  float wk2 = 1.0f / (1.0f + __expf(-(s2 + tg + bias2)));
  float wk3 = 1.0f / (1.0f + __expf(-(s3 + tg + bias2)));

  float oc = ((1.0f - wk0) * r0 + wk0 * p0)
           + ((1.0f - wk1) * r1 + wk1 * p1)
           + ((1.0f - wk2) * r2 + wk2 * p2)
           + ((1.0f - wk3) * r3 + wk3 * p3);
  outbuf[lane * 4 + wave] = oc;
  __syncthreads();

  // coalesced-ish output store: 4 consecutive n per block, 16B chunks
  int c = tid >> 2, wq = tid & 3;
  int gq0 = blockIdx.x * 4;
  int b0i = gq0 >> 13, n0 = gq0 & (N_QRY - 1);
  out[(((size_t)b0i * 64 + c) << 13) + n0 + wq] = outbuf[c * 4 + wq];
}

extern "C" void kernel_launch(void* const* d_in, const int* in_sizes, int n_in,
                              void* d_out, int out_size, void* d_ws, size_t ws_size,
                              hipStream_t stream) {
  (void)in_sizes; (void)n_in; (void)out_size; (void)ws_size;
  const float* original_pts = (const float*)d_in[0];
  const float* query_pts   = (const float*)d_in[1];
  const float* local_feat  = (const float*)d_in[2];
  const float* w0 = (const float*)d_in[3];
  const float* b0 = (const float*)d_in[4];
  const float* g0 = (const float*)d_in[5];
  const float* be0 = (const float*)d_in[6];
  const float* m0 = (const float*)d_in[7];
  const float* v0 = (const float*)d_in[8];
  const float* w1 = (const float*)d_in[9];
  const float* b1 = (const float*)d_in[10];
  const float* g1 = (const float*)d_in[11];
  const float* be1 = (const float*)d_in[12];
  const float* m1 = (const float*)d_in[13];
  const float* v1 = (const float*)d_in[14];
  const float* w2 = (const float*)d_in[15];
  const float* b2 = (const float*)d_in[16];
  float* out = (float*)d_out;

  // workspace layout (16B aligned), total ~11.6 MB
  char* ws = (char*)d_ws;
  float4* pp = (float4*)(ws);                 // 524288 B
  float4* qp = (float4*)(ws + 524288);        // 524288 B
  float*  lfT = (float*)(ws + 1048576);       // 8 MB
  float*  w1T = (float*)(ws + 9437184);       // 16 KB
  float*  w0f = (float*)(ws + 9453568);       // 768 B
  float*  b0f = (float*)(ws + 9454336);       // 256 B
  float*  b1f = (float*)(ws + 9454592);       // 256 B
  int*    knn = (int*)(ws + 9454848);         // 2 MB

  pack_pts<<<128, 256, 0, stream>>>(original_pts, pp, BATCH * M_PTS);
  pack_pts<<<128, 256, 0, stream>>>(query_pts, qp, BATCH * N_QRY);
  transpose_lf<<<512, 256, 0, stream>>>(local_feat, lfT);
  fold_kernel<<<1, 64, 0, stream>>>(w0, b0, g0, be0, m0, v0,
                                    w1, b1, g1, be1, m1, v1,
                                    w0f, b0f, w1T, b1f);
  knn_kernel<<<8192, 256, 0, stream>>>(pp, qp, knn);
  feat_kernel<<<8192, 256, 0, stream>>>(pp, qp, knn, lfT, w1T, w0f, b0f, b1f, w2, b2, out);
}

// Round 2
// 323.002 us; speedup vs baseline: 1.0171x; 1.0171x over previous
//
#include <hip/hip_runtime.h>
#include <cstdint>

#define M_PTS 8192
#define N_QRY 8192
#define BATCH 4

// ---------------- helpers ----------------
__device__ __forceinline__ float d2_exact(float qx, float qy, float qz, float q2, float4 p) {
#pragma clang fp contract(off)
  float dot = (qx * p.x + qy * p.y) + qz * p.z;   // reference op order, no fma
  return (q2 + p.w) - 2.0f * dot;
}

__device__ __forceinline__ unsigned flipf(float d) {
  unsigned u = __float_as_uint(d);
  return u ^ ((unsigned)((int)u >> 31) | 0x80000000u);   // order-preserving float->uint
}

__device__ __forceinline__ int lane_prefix(unsigned long long m) {
  return __builtin_amdgcn_mbcnt_hi((unsigned)(m >> 32),
         __builtin_amdgcn_mbcnt_lo((unsigned)m, 0));
}

__device__ __forceinline__ void ld_lds16(const float4* g, float4* l) {
  __builtin_amdgcn_global_load_lds((const __attribute__((address_space(1))) void*)g,
                                   (__attribute__((address_space(3))) void*)l, 16, 0, 0);
}

// 16th smallest of the 64 lane values via cross-lane bitonic sort (verified R0)
__device__ __forceinline__ float rank16(float v, int lane) {
#pragma unroll
  for (int k = 2; k <= 64; k <<= 1) {
#pragma unroll
    for (int j = k >> 1; j >= 1; j >>= 1) {
      float pv = __shfl_xor(v, j);
      bool keepmin = (((lane & k) == 0) == ((lane & j) == 0));
      float lo = fminf(v, pv), hi = fmaxf(v, pv);
      v = keepmin ? lo : hi;
    }
  }
  return __shfl(v, 15);
}

// ---------------- K0a: pack (x, y, z, x^2+y^2+z^2) ----------------
__global__ void pack_pts(const float* __restrict__ src, float4* __restrict__ dst, int total) {
#pragma clang fp contract(off)
  int i = blockIdx.x * 256 + threadIdx.x;
  if (i >= total) return;
  int b = i >> 13, m = i & (M_PTS - 1);
  const float* s = src + (size_t)b * 3 * M_PTS;
  float x = s[m], y = s[M_PTS + m], z = s[2 * M_PTS + m];
  float ss = (x * x + y * y) + z * z;   // matches jnp.sum(pts**2, axis=1) order
  dst[i] = make_float4(x, y, z, ss);
}

// ---------------- K0b: transpose local_feat (B,64,M) -> (B,M,64) ----------------
__global__ void transpose_lf(const float* __restrict__ lf, float* __restrict__ lfT) {
  __shared__ float tile[64][65];
  int bb = blockIdx.x >> 7;
  int m0 = (blockIdx.x & 127) << 6;
  int tm = threadIdx.x & 63;
  int tc = threadIdx.x >> 6;
  const float* src = lf + (size_t)bb * 64 * M_PTS;
#pragma unroll
  for (int i = 0; i < 16; i++) {
    int ch = i * 4 + tc;
    tile[ch][tm] = src[(size_t)ch * M_PTS + m0 + tm];
  }
  __syncthreads();
  float* dst = lfT + ((size_t)bb * M_PTS + m0) * 64;
#pragma unroll
  for (int i = 0; i < 16; i++) {
    int mm = i * 4 + tc;
    dst[(size_t)mm * 64 + tm] = tile[tm][mm];
  }
}

// ---------------- K1: exact KNN top-16, 2 queries per wave ----------------
// Hot loop key: e = fma(-2qx,px, fma(-2qy,py, fma(-2qz,pz, pw)))  (= d2 - q2 up to
// rounding; ordering-equivalent modulo margin). tau = 16th smallest of 64 lane-mins
// per half guarantees >=16 candidates. Candidates re-scored with the exact reference
// d2 tree before final selection, so the result ordering is bit-identical to R0.
__global__ void __launch_bounds__(256, 2) knn_kernel(const float4* __restrict__ pp,
                                                     const float4* __restrict__ qp,
                                                     int* __restrict__ knn_out) {
  __shared__ float4 spts[2048];          // 32 KB staged point chunk
  __shared__ unsigned cand[8][128];      // 4 KB candidate index buffers (per wave x 2 q)
  const int tid = threadIdx.x;
  const int lane = tid & 63;
  const int wave = tid >> 6;
  const int b = blockIdx.x >> 10;                 // 1024 blocks per batch
  const int qa = blockIdx.x * 8 + wave * 2;       // this wave's two queries
  const float4* pb = pp + ((size_t)b << 13);

  const float4 A4 = qp[qa];
  const float4 B4 = qp[qa + 1];
  const float axA = -2.0f * A4.x, ayA = -2.0f * A4.y, azA = -2.0f * A4.z;
  const float axB = -2.0f * B4.x, ayB = -2.0f * B4.y, azB = -2.0f * B4.z;

  float eA[64], eB[64];
  int cntA = 0, cntB = 0;
  unsigned* cqA = cand[wave * 2 + 0];
  unsigned* cqB = cand[wave * 2 + 1];

  auto passB = [&](const float (&e)[64], float thr, int h, int& cnt, unsigned* cq) {
#pragma unroll
    for (int r = 0; r < 64; r++) {
      bool pred = e[r] <= thr;
      unsigned long long mask = __ballot(pred);
      if (mask) {
        int pos = cnt + lane_prefix(mask);
        if (pred && pos < 128)
          cq[pos] = (unsigned)(h * 4096 + (r >> 5) * 2048 + (r & 31) * 64 + lane);
        cnt += __popcll(mask);
      }
    }
  };

#pragma unroll
  for (int h = 0; h < 2; h++) {
    float mnA = 3.402823466e38f, mnB = 3.402823466e38f;
#pragma unroll
    for (int cc = 0; cc < 2; cc++) {
      const int c = h * 2 + cc;
      __syncthreads();                      // protect spts from previous chunk's readers
#pragma unroll
      for (int i = 0; i < 8; i++) {
        const float4* g = pb + c * 2048 + i * 256 + wave * 64 + lane;
        ld_lds16(g, &spts[i * 256 + wave * 64]);   // wave-uniform LDS base + lane*16
      }
      __syncthreads();                      // drains vmcnt -> data visible
#pragma unroll
      for (int j = 0; j < 32; j++) {
        float4 p = spts[j * 64 + lane];
        float ea = __builtin_fmaf(axA, p.x, __builtin_fmaf(ayA, p.y,
                   __builtin_fmaf(azA, p.z, p.w)));
        float eb = __builtin_fmaf(axB, p.x, __builtin_fmaf(ayB, p.y,
                   __builtin_fmaf(azB, p.z, p.w)));
        eA[cc * 32 + j] = ea;
        eB[cc * 32 + j] = eb;
        mnA = fminf(mnA, ea);
        mnB = fminf(mnB, eb);
      }
    }
    float tauA = rank16(mnA, lane) + 0.01f;   // margin >> fma-vs-exact divergence
    float tauB = rank16(mnB, lane) + 0.01f;
    passB(eA, tauA, h, cntA, cqA);
    passB(eB, tauB, h, cntB, cqB);
  }

  auto finalize = [&](const unsigned* cq, int cnt, int gq,
                      float qx, float qy, float qz, float q2) {
    int E = cnt < 128 ? cnt : 128;            // E >= 32 guaranteed
    unsigned i0 = (lane < E) ? cq[lane] : 0u;
    unsigned i1 = (lane + 64 < E) ? cq[lane + 64] : 0u;
    float4 p0 = pb[i0];                       // parallel L2-hit loads
    float4 p1 = pb[i1];
    unsigned long long k0 = ~0ull, k1 = ~0ull;
    if (lane < E)
      k0 = ((unsigned long long)flipf(d2_exact(qx, qy, qz, q2, p0)) << 32) | i0;
    if (lane + 64 < E)
      k1 = ((unsigned long long)flipf(d2_exact(qx, qy, qz, q2, p1)) << 32) | i1;
    unsigned my = 0;
#pragma unroll
    for (int t = 0; t < 16; t++) {
      unsigned long long m = k0 < k1 ? k0 : k1;
#pragma unroll
      for (int j = 1; j < 64; j <<= 1) {
        unsigned long long o = __shfl_xor(m, j);
        if (o < m) m = o;
      }
      if (lane == t) my = (unsigned)m;
      if (k0 == m) k0 = ~0ull;
      else if (k1 == m) k1 = ~0ull;
    }
    if (lane < 16) knn_out[(size_t)gq * 16 + lane] = (int)my;
  };

  finalize(cqA, cntA, qa,     A4.x, A4.y, A4.z, A4.w);
  finalize(cqB, cntB, qa + 1, B4.x, B4.y, B4.z, B4.w);
}

// ---------------- K2: fused feature pipeline, 16 queries per block ----------------
// lane = channel. w1 row lives in 64 VGPRs per lane (raw weights; BN scale applied
// after accumulation). relbuf/f0v are wave-local: lockstep wave => no barrier needed.
__global__ void __launch_bounds__(256, 3) feat_kernel(
    const float4* __restrict__ pp, const float4* __restrict__ qp,
    const int* __restrict__ knn, const float* __restrict__ lfT,
    const float* __restrict__ w0, const float* __restrict__ b0,
    const float* __restrict__ g0, const float* __restrict__ be0,
    const float* __restrict__ m0, const float* __restrict__ v0,
    const float* __restrict__ w1, const float* __restrict__ b1,
    const float* __restrict__ g1, const float* __restrict__ be1,
    const float* __restrict__ m1, const float* __restrict__ v1,
    const float* __restrict__ w2, const float* __restrict__ b2,
    float* __restrict__ out) {
  __shared__ float4 relbuf[4][16];
  __shared__ float4 f0v[4][64];
  __shared__ float outbuf[64][17];     // +1 pad breaks write-phase bank conflicts
  const int tid = threadIdx.x;
  const int lane = tid & 63;
  const int wave = tid >> 6;
  const int gq0 = blockIdx.x * 16;
  const int b = gq0 >> 13;

  // BN folds (inline; fp order matches R0's fold_kernel)
  const float inv0 = g0[lane] / sqrtf(v0[lane] + 1e-5f);
  const float w00 = w0[lane * 3 + 0] * inv0;
  const float w01 = w0[lane * 3 + 1] * inv0;
  const float w02 = w0[lane * 3 + 2] * inv0;
  const float bb0 = (b0[lane] - m0[lane]) * inv0 + be0[lane];
  const float inv1 = g1[lane] / sqrtf(v1[lane] + 1e-5f);
  const float bb1 = (b1[lane] - m1[lane]) * inv1 + be1[lane];

  float w1s[64];
#pragma unroll
  for (int i = 0; i < 16; i++) {
    float4 t = ((const float4*)(w1 + (size_t)lane * 64))[i];
    w1s[i * 4 + 0] = t.x; w1s[i * 4 + 1] = t.y;
    w1s[i * 4 + 2] = t.z; w1s[i * 4 + 3] = t.w;
  }
  const float w2a = w2[lane], w2b = w2[64 + lane];
  const float bias2 = b2[0];
  const float4* pb = pp + ((size_t)b << 13);
  const float* lfb = lfT + (((size_t)b << 13)) * 64;

  for (int qi = 0; qi < 4; qi++) {
    const int gq = gq0 + wave * 4 + qi;
    const float4 q4 = qp[gq];
    int nk = knn[(size_t)gq * 16 + (lane & 15)];
    float4 pk = pb[nk];
    if (lane < 16)
      relbuf[wave][lane] = make_float4(pk.x - q4.x, pk.y - q4.y, pk.z - q4.z, 0.0f);
    // wave-local RAW: lgkmcnt ordering suffices, no barrier

    float g = 0.0f, f0 = 0, f1 = 0, f2 = 0, f3 = 0;
#pragma unroll
    for (int k = 0; k < 16; k++) {
      float4 r = relbuf[wave][k];
      float y = fmaxf(0.0f, w00 * r.x + w01 * r.y + w02 * r.z + bb0);
      g = fmaxf(g, y);
      if (k == 0) f0 = y; else if (k == 1) f1 = y;
      else if (k == 2) f2 = y; else if (k == 3) f3 = y;
    }
    f0v[wave][lane] = make_float4(f0, f1, f2, f3);

    float a0 = 0, a1 = 0, a2 = 0, a3 = 0;
#pragma unroll
    for (int c2 = 0; c2 < 64; c2++) {
      float w = w1s[c2];                 // register (compile-time index)
      float4 fb = f0v[wave][c2];         // LDS broadcast
      a0 = fmaf(w, fb.x, a0); a1 = fmaf(w, fb.y, a1);
      a2 = fmaf(w, fb.z, a2); a3 = fmaf(w, fb.w, a3);
    }
    float r0 = fmaxf(0.0f, fmaf(a0, inv1, bb1));
    float r1 = fmaxf(0.0f, fmaf(a1, inv1, bb1));
    float r2 = fmaxf(0.0f, fmaf(a2, inv1, bb1));
    float r3 = fmaxf(0.0f, fmaf(a3, inv1, bb1));

    int i0 = __shfl(nk, 0), i1 = __shfl(nk, 1), i2 = __shfl(nk, 2), i3 = __shfl(nk, 3);
    float p0 = lfb[(size_t)i0 * 64 + lane];
    float p1 = lfb[(size_t)i1 * 64 + lane];
    float p2 = lfb[(size_t)i2 * 64 + lane];
    float p3 = lfb[(size_t)i3 * 64 + lane];

    float s0 = w2a * r0, s1 = w2a * r1, s2 = w2a * r2, s3 = w2a * r3, tg = w2b * g;
#pragma unroll
    for (int j = 1; j < 64; j <<= 1) {
      s0 += __shfl_xor(s0, j);
      s1 += __shfl_xor(s1, j);
      s2 += __shfl_xor(s2, j);
      s3 += __shfl_xor(s3, j);
      tg += __shfl_xor(tg, j);
    }
    float wk0 = 1.0f / (1.0f + __expf(-(s0 + tg + bias2)));
    float wk1 = 1.0f / (1.0f + __expf(-(s1 + tg + bias2)));
    float wk2 = 1.0f / (1.0f + __expf(-(s2 + tg + bias2)));
    float wk3 = 1.0f / (1.0f + __expf(-(s3 + tg + bias2)));

    float oc = ((1.0f - wk0) * r0 + wk0 * p0)
             + ((1.0f - wk1) * r1 + wk1 * p1)
             + ((1.0f - wk2) * r2 + wk2 * p2)
             + ((1.0f - wk3) * r3 + wk3 * p3);
    outbuf[lane][wave * 4 + qi] = oc;
  }
  __syncthreads();

  // coalesced output: thread t -> channel c = t>>2, 4 queries via float4
  int c = tid >> 2, j = tid & 3;
  float4 o4 = make_float4(outbuf[c][j * 4 + 0], outbuf[c][j * 4 + 1],
                          outbuf[c][j * 4 + 2], outbuf[c][j * 4 + 3]);
  *(float4*)(out + (((size_t)(b * 64 + c)) << 13) + (gq0 & (N_QRY - 1)) + j * 4) = o4;
}

extern "C" void kernel_launch(void* const* d_in, const int* in_sizes, int n_in,
                              void* d_out, int out_size, void* d_ws, size_t ws_size,
                              hipStream_t stream) {
  (void)in_sizes; (void)n_in; (void)out_size; (void)ws_size;
  const float* original_pts = (const float*)d_in[0];
  const float* query_pts   = (const float*)d_in[1];
  const float* local_feat  = (const float*)d_in[2];
  const float* w0 = (const float*)d_in[3];
  const float* b0 = (const float*)d_in[4];
  const float* g0 = (const float*)d_in[5];
  const float* be0 = (const float*)d_in[6];
  const float* m0 = (const float*)d_in[7];
  const float* v0 = (const float*)d_in[8];
  const float* w1 = (const float*)d_in[9];
  const float* b1 = (const float*)d_in[10];
  const float* g1 = (const float*)d_in[11];
  const float* be1 = (const float*)d_in[12];
  const float* m1 = (const float*)d_in[13];
  const float* v1 = (const float*)d_in[14];
  const float* w2 = (const float*)d_in[15];
  const float* b2 = (const float*)d_in[16];
  float* out = (float*)d_out;

  // workspace layout (16B aligned), total ~11.5 MB
  char* ws = (char*)d_ws;
  float4* pp  = (float4*)(ws);                 // 512 KB
  float4* qp  = (float4*)(ws + 524288);        // 512 KB
  float*  lfT = (float*)(ws + 1048576);        // 8 MB
  int*    knn = (int*)(ws + 9437184);          // 2 MB

  pack_pts<<<128, 256, 0, stream>>>(original_pts, pp, BATCH * M_PTS);
  pack_pts<<<128, 256, 0, stream>>>(query_pts, qp, BATCH * N_QRY);
  transpose_lf<<<512, 256, 0, stream>>>(local_feat, lfT);
  knn_kernel<<<4096, 256, 0, stream>>>(pp, qp, knn);
  feat_kernel<<<2048, 256, 0, stream>>>(pp, qp, knn, lfT,
                                        w0, b0, g0, be0, m0, v0,
                                        w1, b1, g1, be1, m1, v1,
                                        w2, b2, out);
}